// Round 3
// baseline (332.400 us; speedup 1.0000x reference)
//
#include <hip/hip_runtime.h>
#include <math.h>

constexpr int NN = 100000;   // nodes
constexpr int NE = 1250000;  // edges
constexpr int NF = 64;       // input features
constexpr int NH = 16;       // hidden
constexpr int NC = 7;        // classes

constexpr int BKT_SHIFT = 7;                 // 128 nodes per bucket
constexpr int BKT_NODES = 1 << BKT_SHIFT;    // 128
constexpr int NBUCKET = (NN + BKT_NODES - 1) / BKT_NODES;  // 782
constexpr int BSTRIDE = 2048;                // capacity per bucket (mean 1598, +11 sigma)
constexpr int EPB = 8192;                    // edges per bucketing block
constexpr int NBLK_BUCKET = (NE + EPB - 1) / EPB;          // 153
constexpr int CUR_PAD = 16;                  // pad cursors to own 64B line

// ---------------- Kernel 1: y = x @ W1 ; A = y, B = y + b1 ----------------
__global__ __launch_bounds__(256) void k1_gemm(
    const float* __restrict__ x, const float* __restrict__ W1,
    const float* __restrict__ b1, float* __restrict__ A, float* __restrict__ B) {
    __shared__ float w[NF * NH];   // 4 KB
    __shared__ float bias[NH];
    for (int i = threadIdx.x; i < NF * NH; i += blockDim.x) w[i] = W1[i];
    if (threadIdx.x < NH) bias[threadIdx.x] = b1[threadIdx.x];
    __syncthreads();
    int node = blockIdx.x * blockDim.x + threadIdx.x;
    if (node >= NN) return;

    float acc[NH];
#pragma unroll
    for (int j = 0; j < NH; ++j) acc[j] = 0.f;

    const float4* xr = (const float4*)(x + (size_t)node * NF);
#pragma unroll
    for (int k4 = 0; k4 < NF / 4; ++k4) {
        float4 xv = xr[k4];
        int k = k4 * 4;
#pragma unroll
        for (int j = 0; j < NH; ++j) {
            acc[j] += xv.x * w[(k + 0) * NH + j]
                    + xv.y * w[(k + 1) * NH + j]
                    + xv.z * w[(k + 2) * NH + j]
                    + xv.w * w[(k + 3) * NH + j];
        }
    }
    float4* Ar = (float4*)(A + (size_t)node * NH);
    float4* Br = (float4*)(B + (size_t)node * NH);
#pragma unroll
    for (int q = 0; q < NH / 4; ++q) {
        float4 a;
        a.x = acc[q * 4 + 0]; a.y = acc[q * 4 + 1];
        a.z = acc[q * 4 + 2]; a.w = acc[q * 4 + 3];
        Ar[q] = a;
        float4 bv;
        bv.x = a.x + bias[q * 4 + 0]; bv.y = a.y + bias[q * 4 + 1];
        bv.z = a.z + bias[q * 4 + 2]; bv.w = a.w + bias[q * 4 + 3];
        Br[q] = bv;
    }
}

// ------- Bucketing: group edges by dst>>7 into contiguous runs, packed -------
// pack = (src << 7) | (dst & 127); slot = bucket*BSTRIDE + chunkBase + rank
__global__ __launch_bounds__(1024) void k_bucket(
    const int* __restrict__ src, const int* __restrict__ dst,
    int* __restrict__ gcur, unsigned* __restrict__ gbuf) {
    __shared__ int cnt[NBUCKET];
    __shared__ int gb[NBUCKET];
    for (int i = threadIdx.x; i < NBUCKET; i += 1024) cnt[i] = 0;
    __syncthreads();

    unsigned pk[8];
    int bk[8];
    int rk[8];
    int base = blockIdx.x * EPB;
#pragma unroll
    for (int k = 0; k < 8; ++k) {
        int e = base + k * 1024 + threadIdx.x;
        bk[k] = -1;
        if (e < NE) {
            int s = src[e];
            int d = dst[e];
            int b = d >> BKT_SHIFT;
            bk[k] = b;
            pk[k] = ((unsigned)s << BKT_SHIFT) | (unsigned)(d & (BKT_NODES - 1));
            rk[k] = atomicAdd(&cnt[b], 1);   // LDS atomic, ~10/counter
        }
    }
    __syncthreads();
    for (int b = threadIdx.x; b < NBUCKET; b += 1024) {
        int c = cnt[b];
        gb[b] = (c > 0) ? atomicAdd(&gcur[b * CUR_PAD], c) : 0;
    }
    __syncthreads();
#pragma unroll
    for (int k = 0; k < 8; ++k) {
        if (bk[k] >= 0) {
            int pos = gb[bk[k]] + rk[k];
            if (pos < BSTRIDE)   // statistically impossible overflow guard
                gbuf[(size_t)bk[k] * BSTRIDE + pos] = pk[k];
        }
    }
}

// ------- Aggregation: one block per bucket, B-slice in LDS, LDS f32 atomics -------
__global__ __launch_bounds__(512) void k_agg(
    const float* __restrict__ A, float* __restrict__ B,
    const int* __restrict__ gcur, const unsigned* __restrict__ gbuf) {
    __shared__ float Bl[BKT_NODES * 17];   // pad 16->17 to spread banks
    int b = blockIdx.x;
    int nodeBase = b << BKT_SHIFT;

    for (int i = threadIdx.x; i < BKT_NODES * NH; i += 512) {
        int row = i >> 4, c = i & 15;
        int node = nodeBase + row;
        Bl[row * 17 + c] = (node < NN) ? B[(size_t)node * NH + c] : 0.f;
    }
    __syncthreads();

    int cnt = gcur[b * CUR_PAD];
    if (cnt > BSTRIDE) cnt = BSTRIDE;
    int q = (threadIdx.x & 3) * 4;
    for (int i0 = (threadIdx.x >> 2); i0 < cnt; i0 += 128) {
        unsigned u = gbuf[(size_t)b * BSTRIDE + i0];
        int s = u >> BKT_SHIFT;
        int dl = u & (BKT_NODES - 1);
        float4 v = *(const float4*)(A + (size_t)s * NH + q);
        float* p = &Bl[dl * 17 + q];
        atomicAdd(p + 0, v.x);
        atomicAdd(p + 1, v.y);
        atomicAdd(p + 2, v.z);
        atomicAdd(p + 3, v.w);
    }
    __syncthreads();

    for (int i = threadIdx.x; i < BKT_NODES * NH; i += 512) {
        int row = i >> 4, c = i & 15;
        int node = nodeBase + row;
        if (node < NN) B[(size_t)node * NH + c] = Bl[row * 17 + c];
    }
}

// --- Kernel 3: h=relu(B); t=relu(h@W2+b2); z=t@W3; A=z, B=z+b3 (in place) ---
__global__ __launch_bounds__(256) void k3_mid(
    float* __restrict__ A, float* __restrict__ B,
    const float* __restrict__ W2, const float* __restrict__ b2,
    const float* __restrict__ W3, const float* __restrict__ b3) {
    __shared__ float w2[NH * NH], w3[NH * NH];
    __shared__ float bb2[NH], bb3[NH];
    for (int i = threadIdx.x; i < NH * NH; i += blockDim.x) {
        w2[i] = W2[i];
        w3[i] = W3[i];
    }
    if (threadIdx.x < NH) {
        bb2[threadIdx.x] = b2[threadIdx.x];
        bb3[threadIdx.x] = b3[threadIdx.x];
    }
    __syncthreads();
    int node = blockIdx.x * blockDim.x + threadIdx.x;
    if (node >= NN) return;

    float h[NH];
    float4* Brow = (float4*)(B + (size_t)node * NH);
#pragma unroll
    for (int q = 0; q < 4; ++q) {
        float4 v = Brow[q];
        h[q * 4 + 0] = fmaxf(v.x, 0.f);
        h[q * 4 + 1] = fmaxf(v.y, 0.f);
        h[q * 4 + 2] = fmaxf(v.z, 0.f);
        h[q * 4 + 3] = fmaxf(v.w, 0.f);
    }
    float t[NH];
#pragma unroll
    for (int j = 0; j < NH; ++j) t[j] = bb2[j];
#pragma unroll
    for (int k = 0; k < NH; ++k) {
        float hk = h[k];
#pragma unroll
        for (int j = 0; j < NH; ++j) t[j] += hk * w2[k * NH + j];
    }
#pragma unroll
    for (int j = 0; j < NH; ++j) t[j] = fmaxf(t[j], 0.f);

    float z[NH];
#pragma unroll
    for (int j = 0; j < NH; ++j) z[j] = 0.f;
#pragma unroll
    for (int k = 0; k < NH; ++k) {
        float tk = t[k];
#pragma unroll
        for (int j = 0; j < NH; ++j) z[j] += tk * w3[k * NH + j];
    }
    float4* Arow = (float4*)(A + (size_t)node * NH);
#pragma unroll
    for (int q = 0; q < 4; ++q) {
        float4 a;
        a.x = z[q * 4 + 0]; a.y = z[q * 4 + 1];
        a.z = z[q * 4 + 2]; a.w = z[q * 4 + 3];
        Arow[q] = a;
        float4 bv;
        bv.x = a.x + bb3[q * 4 + 0]; bv.y = a.y + bb3[q * 4 + 1];
        bv.z = a.z + bb3[q * 4 + 2]; bv.w = a.w + bb3[q * 4 + 3];
        Brow[q] = bv;
    }
}

// ---- Kernel 5: h=relu(B); o=h@W4+b4; out = log_softmax(o) ----
__global__ __launch_bounds__(256) void k5_out(
    const float* __restrict__ B, const float* __restrict__ W4,
    const float* __restrict__ b4, float* __restrict__ out) {
    __shared__ float w4[NH * NC];
    __shared__ float bb4[NC];
    for (int i = threadIdx.x; i < NH * NC; i += blockDim.x) w4[i] = W4[i];
    if (threadIdx.x < NC) bb4[threadIdx.x] = b4[threadIdx.x];
    __syncthreads();
    int node = blockIdx.x * blockDim.x + threadIdx.x;
    if (node >= NN) return;

    float h[NH];
    const float4* Brow = (const float4*)(B + (size_t)node * NH);
#pragma unroll
    for (int q = 0; q < 4; ++q) {
        float4 v = Brow[q];
        h[q * 4 + 0] = fmaxf(v.x, 0.f);
        h[q * 4 + 1] = fmaxf(v.y, 0.f);
        h[q * 4 + 2] = fmaxf(v.z, 0.f);
        h[q * 4 + 3] = fmaxf(v.w, 0.f);
    }
    float o[NC];
#pragma unroll
    for (int c = 0; c < NC; ++c) o[c] = bb4[c];
#pragma unroll
    for (int k = 0; k < NH; ++k) {
        float hk = h[k];
#pragma unroll
        for (int c = 0; c < NC; ++c) o[c] += hk * w4[k * NC + c];
    }
    float m = o[0];
#pragma unroll
    for (int c = 1; c < NC; ++c) m = fmaxf(m, o[c]);
    float s = 0.f;
#pragma unroll
    for (int c = 0; c < NC; ++c) s += expf(o[c] - m);
    float ls = m + logf(s);
    float* op = out + (size_t)node * NC;
#pragma unroll
    for (int c = 0; c < NC; ++c) op[c] = o[c] - ls;
}

extern "C" void kernel_launch(void* const* d_in, const int* in_sizes, int n_in,
                              void* d_out, int out_size, void* d_ws, size_t ws_size,
                              hipStream_t stream) {
    const float* x  = (const float*)d_in[0];
    const int*   ei = (const int*)d_in[1];   // [2, NE] flat: src then dst
    const float* W1 = (const float*)d_in[2];
    const float* b1 = (const float*)d_in[3];
    const float* W2 = (const float*)d_in[4];
    const float* b2 = (const float*)d_in[5];
    const float* W3 = (const float*)d_in[6];
    const float* b3 = (const float*)d_in[7];
    const float* W4 = (const float*)d_in[8];
    const float* b4 = (const float*)d_in[9];
    float* out = (float*)d_out;

    const int* src = ei;
    const int* dst = ei + NE;

    // workspace layout (16B-aligned)
    float*    A    = (float*)d_ws;                          // [NN, NH]  6.4 MB
    float*    B    = A + (size_t)NN * NH;                   // [NN, NH]  6.4 MB
    int*      gcur = (int*)(B + (size_t)NN * NH);           // [NBUCKET*16] 50 KB
    unsigned* gbuf = (unsigned*)(gcur + NBUCKET * CUR_PAD); // [NBUCKET*BSTRIDE] 6.4 MB

    const int nodeBlocks = (NN + 255) / 256;

    hipMemsetAsync(gcur, 0, (size_t)NBUCKET * CUR_PAD * sizeof(int), stream);
    k1_gemm<<<nodeBlocks, 256, 0, stream>>>(x, W1, b1, A, B);
    k_bucket<<<NBLK_BUCKET, 1024, 0, stream>>>(src, dst, gcur, gbuf);

    // conv1 aggregation + MLP
    k_agg<<<NBUCKET, 512, 0, stream>>>(A, B, gcur, gbuf);
    k3_mid<<<nodeBlocks, 256, 0, stream>>>(A, B, W2, b2, W3, b3);

    // conv2 aggregation + head
    k_agg<<<NBUCKET, 512, 0, stream>>>(A, B, gcur, gbuf);
    k5_out<<<nodeBlocks, 256, 0, stream>>>(B, W4, b4, out);
}

// Round 4
// 101.610 us; speedup vs baseline: 3.2713x; 3.2713x over previous
//
#include <hip/hip_runtime.h>
#include <math.h>

constexpr int NN = 100000;   // nodes
constexpr int NE = 1250000;  // edges
constexpr int NF = 64;       // input features
constexpr int NH = 16;       // hidden
constexpr int NC = 7;        // classes

constexpr int BKT_SHIFT = 7;                 // 128 nodes per bucket
constexpr int BKT_NODES = 1 << BKT_SHIFT;    // 128
constexpr int NBUCKET = (NN + BKT_NODES - 1) / BKT_NODES;  // 782
constexpr int BSTRIDE = 2048;                // capacity per bucket (mean 1598, +11 sigma)
constexpr int EPB = 8192;                    // edges per bucketing block
constexpr int NBLK_BUCKET = (NE + EPB - 1) / EPB;          // 153
constexpr int CUR_PAD = 16;                  // pad cursors to own 64B line

// ---------------- Kernel 1: y = x @ W1 ; A = y, B = y + b1 ----------------
__global__ __launch_bounds__(256) void k1_gemm(
    const float* __restrict__ x, const float* __restrict__ W1,
    const float* __restrict__ b1, float* __restrict__ A, float* __restrict__ B) {
    __shared__ float w[NF * NH];   // 4 KB
    __shared__ float bias[NH];
    for (int i = threadIdx.x; i < NF * NH; i += blockDim.x) w[i] = W1[i];
    if (threadIdx.x < NH) bias[threadIdx.x] = b1[threadIdx.x];
    __syncthreads();
    int node = blockIdx.x * blockDim.x + threadIdx.x;
    if (node >= NN) return;

    float acc[NH];
#pragma unroll
    for (int j = 0; j < NH; ++j) acc[j] = 0.f;

    const float4* xr = (const float4*)(x + (size_t)node * NF);
#pragma unroll
    for (int k4 = 0; k4 < NF / 4; ++k4) {
        float4 xv = xr[k4];
        int k = k4 * 4;
#pragma unroll
        for (int j = 0; j < NH; ++j) {
            acc[j] += xv.x * w[(k + 0) * NH + j]
                    + xv.y * w[(k + 1) * NH + j]
                    + xv.z * w[(k + 2) * NH + j]
                    + xv.w * w[(k + 3) * NH + j];
        }
    }
    float4* Ar = (float4*)(A + (size_t)node * NH);
    float4* Br = (float4*)(B + (size_t)node * NH);
#pragma unroll
    for (int q = 0; q < NH / 4; ++q) {
        float4 a;
        a.x = acc[q * 4 + 0]; a.y = acc[q * 4 + 1];
        a.z = acc[q * 4 + 2]; a.w = acc[q * 4 + 3];
        Ar[q] = a;
        float4 bv;
        bv.x = a.x + bias[q * 4 + 0]; bv.y = a.y + bias[q * 4 + 1];
        bv.z = a.z + bias[q * 4 + 2]; bv.w = a.w + bias[q * 4 + 3];
        Br[q] = bv;
    }
}

// ------- Bucketing: group edges by dst>>7 into contiguous runs, packed -------
// pack = (src << 7) | (dst & 127); slot = bucket*BSTRIDE + chunkBase + rank
__global__ __launch_bounds__(1024) void k_bucket(
    const int* __restrict__ src, const int* __restrict__ dst,
    int* __restrict__ gcur, unsigned* __restrict__ gbuf) {
    __shared__ int cnt[NBUCKET];
    __shared__ int gb[NBUCKET];
    for (int i = threadIdx.x; i < NBUCKET; i += 1024) cnt[i] = 0;
    __syncthreads();

    unsigned pk[8];
    int bk[8];
    int rk[8];
    int base = blockIdx.x * EPB;
#pragma unroll
    for (int k = 0; k < 8; ++k) {
        int e = base + k * 1024 + threadIdx.x;
        bk[k] = -1;
        if (e < NE) {
            int s = src[e];
            int d = dst[e];
            int b = d >> BKT_SHIFT;
            bk[k] = b;
            pk[k] = ((unsigned)s << BKT_SHIFT) | (unsigned)(d & (BKT_NODES - 1));
            rk[k] = atomicAdd(&cnt[b], 1);   // LDS int atomic (native)
        }
    }
    __syncthreads();
    for (int b = threadIdx.x; b < NBUCKET; b += 1024) {
        int c = cnt[b];
        gb[b] = (c > 0) ? atomicAdd(&gcur[b * CUR_PAD], c) : 0;
    }
    __syncthreads();
#pragma unroll
    for (int k = 0; k < 8; ++k) {
        if (bk[k] >= 0) {
            int pos = gb[bk[k]] + rk[k];
            if (pos < BSTRIDE)   // statistically impossible overflow guard
                gbuf[(size_t)bk[k] * BSTRIDE + pos] = pk[k];
        }
    }
}

// ------- Aggregation: one block per bucket; LDS counting sort by local dst,
//         then per-node register-accumulated gather. NO f32 atomics. -------
__global__ __launch_bounds__(512) void k_agg(
    const float* __restrict__ A, float* __restrict__ B,
    const int* __restrict__ gcur, const unsigned* __restrict__ gbuf) {
    __shared__ unsigned stage[BSTRIDE];   // raw packed edges   (8 KB)
    __shared__ unsigned eSrc[BSTRIDE];    // src sorted by dl   (8 KB)
    __shared__ int cnt[BKT_NODES];
    __shared__ int off[BKT_NODES];        // inclusive scan of cnt
    __shared__ int cur[BKT_NODES];        // scatter cursor

    int b = blockIdx.x;
    int tid = threadIdx.x;
    int n = gcur[b * CUR_PAD];
    if (n > BSTRIDE) n = BSTRIDE;

    if (tid < BKT_NODES) cnt[tid] = 0;
    __syncthreads();

    // load packed edges to LDS + histogram by local dst
    for (int i = tid; i < n; i += 512) {
        unsigned u = gbuf[(size_t)b * BSTRIDE + i];
        stage[i] = u;
        atomicAdd(&cnt[u & (BKT_NODES - 1)], 1);
    }
    __syncthreads();

    // Hillis-Steele inclusive scan over 128 counters
    if (tid < BKT_NODES) off[tid] = cnt[tid];
    __syncthreads();
    for (int d = 1; d < BKT_NODES; d <<= 1) {
        int v = 0;
        if (tid < BKT_NODES && tid >= d) v = off[tid - d];
        __syncthreads();
        if (tid < BKT_NODES) off[tid] += v;
        __syncthreads();
    }
    if (tid < BKT_NODES) cur[tid] = off[tid] - cnt[tid];   // exclusive start
    __syncthreads();

    // scatter: ticket via native int LDS atomic; store src only
    for (int i = tid; i < n; i += 512) {
        unsigned u = stage[i];
        int pos = atomicAdd(&cur[u & (BKT_NODES - 1)], 1);
        eSrc[pos] = u >> BKT_SHIFT;
    }
    __syncthreads();

    // gather: 4 threads per node, register accumulation, 2-deep unroll
    int node = tid >> 2;
    int q = (tid & 3) * 4;
    int gnode = (b << BKT_SHIFT) + node;
    int end = off[node];
    int start = end - cnt[node];

    float4 bq = {0.f, 0.f, 0.f, 0.f};
    if (gnode < NN) bq = *(const float4*)(B + (size_t)gnode * NH + q);

    float4 a0 = {0.f, 0.f, 0.f, 0.f}, a1 = {0.f, 0.f, 0.f, 0.f};
    int j = start;
    for (; j + 2 <= end; j += 2) {
        int s0 = eSrc[j];
        int s1 = eSrc[j + 1];
        float4 v0 = *(const float4*)(A + (size_t)s0 * NH + q);
        float4 v1 = *(const float4*)(A + (size_t)s1 * NH + q);
        a0.x += v0.x; a0.y += v0.y; a0.z += v0.z; a0.w += v0.w;
        a1.x += v1.x; a1.y += v1.y; a1.z += v1.z; a1.w += v1.w;
    }
    if (j < end) {
        int s0 = eSrc[j];
        float4 v0 = *(const float4*)(A + (size_t)s0 * NH + q);
        a0.x += v0.x; a0.y += v0.y; a0.z += v0.z; a0.w += v0.w;
    }
    if (gnode < NN) {
        bq.x += a0.x + a1.x; bq.y += a0.y + a1.y;
        bq.z += a0.z + a1.z; bq.w += a0.w + a1.w;
        *(float4*)(B + (size_t)gnode * NH + q) = bq;
    }
}

// --- Kernel 3: h=relu(B); t=relu(h@W2+b2); z=t@W3; A=z, B=z+b3 (in place) ---
__global__ __launch_bounds__(256) void k3_mid(
    float* __restrict__ A, float* __restrict__ B,
    const float* __restrict__ W2, const float* __restrict__ b2,
    const float* __restrict__ W3, const float* __restrict__ b3) {
    __shared__ float w2[NH * NH], w3[NH * NH];
    __shared__ float bb2[NH], bb3[NH];
    for (int i = threadIdx.x; i < NH * NH; i += blockDim.x) {
        w2[i] = W2[i];
        w3[i] = W3[i];
    }
    if (threadIdx.x < NH) {
        bb2[threadIdx.x] = b2[threadIdx.x];
        bb3[threadIdx.x] = b3[threadIdx.x];
    }
    __syncthreads();
    int node = blockIdx.x * blockDim.x + threadIdx.x;
    if (node >= NN) return;

    float h[NH];
    float4* Brow = (float4*)(B + (size_t)node * NH);
#pragma unroll
    for (int q = 0; q < 4; ++q) {
        float4 v = Brow[q];
        h[q * 4 + 0] = fmaxf(v.x, 0.f);
        h[q * 4 + 1] = fmaxf(v.y, 0.f);
        h[q * 4 + 2] = fmaxf(v.z, 0.f);
        h[q * 4 + 3] = fmaxf(v.w, 0.f);
    }
    float t[NH];
#pragma unroll
    for (int j = 0; j < NH; ++j) t[j] = bb2[j];
#pragma unroll
    for (int k = 0; k < NH; ++k) {
        float hk = h[k];
#pragma unroll
        for (int j = 0; j < NH; ++j) t[j] += hk * w2[k * NH + j];
    }
#pragma unroll
    for (int j = 0; j < NH; ++j) t[j] = fmaxf(t[j], 0.f);

    float z[NH];
#pragma unroll
    for (int j = 0; j < NH; ++j) z[j] = 0.f;
#pragma unroll
    for (int k = 0; k < NH; ++k) {
        float tk = t[k];
#pragma unroll
        for (int j = 0; j < NH; ++j) z[j] += tk * w3[k * NH + j];
    }
    float4* Arow = (float4*)(A + (size_t)node * NH);
#pragma unroll
    for (int q = 0; q < 4; ++q) {
        float4 a;
        a.x = z[q * 4 + 0]; a.y = z[q * 4 + 1];
        a.z = z[q * 4 + 2]; a.w = z[q * 4 + 3];
        Arow[q] = a;
        float4 bv;
        bv.x = a.x + bb3[q * 4 + 0]; bv.y = a.y + bb3[q * 4 + 1];
        bv.z = a.z + bb3[q * 4 + 2]; bv.w = a.w + bb3[q * 4 + 3];
        Brow[q] = bv;
    }
}

// ---- Kernel 5: h=relu(B); o=h@W4+b4; out = log_softmax(o) ----
__global__ __launch_bounds__(256) void k5_out(
    const float* __restrict__ B, const float* __restrict__ W4,
    const float* __restrict__ b4, float* __restrict__ out) {
    __shared__ float w4[NH * NC];
    __shared__ float bb4[NC];
    for (int i = threadIdx.x; i < NH * NC; i += blockDim.x) w4[i] = W4[i];
    if (threadIdx.x < NC) bb4[threadIdx.x] = b4[threadIdx.x];
    __syncthreads();
    int node = blockIdx.x * blockDim.x + threadIdx.x;
    if (node >= NN) return;

    float h[NH];
    const float4* Brow = (const float4*)(B + (size_t)node * NH);
#pragma unroll
    for (int q = 0; q < 4; ++q) {
        float4 v = Brow[q];
        h[q * 4 + 0] = fmaxf(v.x, 0.f);
        h[q * 4 + 1] = fmaxf(v.y, 0.f);
        h[q * 4 + 2] = fmaxf(v.z, 0.f);
        h[q * 4 + 3] = fmaxf(v.w, 0.f);
    }
    float o[NC];
#pragma unroll
    for (int c = 0; c < NC; ++c) o[c] = bb4[c];
#pragma unroll
    for (int k = 0; k < NH; ++k) {
        float hk = h[k];
#pragma unroll
        for (int c = 0; c < NC; ++c) o[c] += hk * w4[k * NC + c];
    }
    float m = o[0];
#pragma unroll
    for (int c = 1; c < NC; ++c) m = fmaxf(m, o[c]);
    float s = 0.f;
#pragma unroll
    for (int c = 0; c < NC; ++c) s += expf(o[c] - m);
    float ls = m + logf(s);
    float* op = out + (size_t)node * NC;
#pragma unroll
    for (int c = 0; c < NC; ++c) op[c] = o[c] - ls;
}

extern "C" void kernel_launch(void* const* d_in, const int* in_sizes, int n_in,
                              void* d_out, int out_size, void* d_ws, size_t ws_size,
                              hipStream_t stream) {
    const float* x  = (const float*)d_in[0];
    const int*   ei = (const int*)d_in[1];   // [2, NE] flat: src then dst
    const float* W1 = (const float*)d_in[2];
    const float* b1 = (const float*)d_in[3];
    const float* W2 = (const float*)d_in[4];
    const float* b2 = (const float*)d_in[5];
    const float* W3 = (const float*)d_in[6];
    const float* b3 = (const float*)d_in[7];
    const float* W4 = (const float*)d_in[8];
    const float* b4 = (const float*)d_in[9];
    float* out = (float*)d_out;

    const int* src = ei;
    const int* dst = ei + NE;

    // workspace layout (16B-aligned)
    float*    A    = (float*)d_ws;                          // [NN, NH]  6.4 MB
    float*    B    = A + (size_t)NN * NH;                   // [NN, NH]  6.4 MB
    int*      gcur = (int*)(B + (size_t)NN * NH);           // [NBUCKET*16] 50 KB
    unsigned* gbuf = (unsigned*)(gcur + NBUCKET * CUR_PAD); // [NBUCKET*BSTRIDE] 6.4 MB

    const int nodeBlocks = (NN + 255) / 256;

    hipMemsetAsync(gcur, 0, (size_t)NBUCKET * CUR_PAD * sizeof(int), stream);
    k1_gemm<<<nodeBlocks, 256, 0, stream>>>(x, W1, b1, A, B);
    k_bucket<<<NBLK_BUCKET, 1024, 0, stream>>>(src, dst, gcur, gbuf);

    // conv1 aggregation + MLP
    k_agg<<<NBUCKET, 512, 0, stream>>>(A, B, gcur, gbuf);
    k3_mid<<<nodeBlocks, 256, 0, stream>>>(A, B, W2, b2, W3, b3);

    // conv2 aggregation + head
    k_agg<<<NBUCKET, 512, 0, stream>>>(A, B, gcur, gbuf);
    k5_out<<<nodeBlocks, 256, 0, stream>>>(B, W4, b4, out);
}

// Round 5
// 97.783 us; speedup vs baseline: 3.3994x; 1.0391x over previous
//
#include <hip/hip_runtime.h>
#include <math.h>

constexpr int NN = 100000;   // nodes
constexpr int NE = 1250000;  // edges
constexpr int NF = 64;       // input features
constexpr int NH = 16;       // hidden
constexpr int NC = 7;        // classes

constexpr int BKT_SHIFT = 7;                 // 128 nodes per bucket
constexpr int BKT_NODES = 1 << BKT_SHIFT;    // 128
constexpr int NBUCKET = (NN + BKT_NODES - 1) / BKT_NODES;  // 782
constexpr int BSTRIDE = 2048;                // capacity per bucket (mean 1598, +11 sigma)
constexpr int EPB = 8192;                    // edges per bucketing block
constexpr int NBLK_BUCKET = (NE + EPB - 1) / EPB;          // 153
constexpr int CUR_PAD = 16;                  // pad cursors to own 64B line

// ------- Kernel 1: y = x @ W1 ; A = y, B = y + b1 ; also zero gcur -------
__global__ __launch_bounds__(256) void k1_gemm(
    const float* __restrict__ x, const float* __restrict__ W1,
    const float* __restrict__ b1, float* __restrict__ A, float* __restrict__ B,
    int* __restrict__ gcur) {
    // zero the bucket cursors (replaces a pathologically slow 50KB memset)
    int gtid = blockIdx.x * 256 + threadIdx.x;
    if (gtid < NBUCKET * CUR_PAD) gcur[gtid] = 0;

    __shared__ float w[NF * NH];   // 4 KB
    __shared__ float bias[NH];
    for (int i = threadIdx.x; i < NF * NH; i += blockDim.x) w[i] = W1[i];
    if (threadIdx.x < NH) bias[threadIdx.x] = b1[threadIdx.x];
    __syncthreads();
    int node = gtid;
    if (node >= NN) return;

    float acc[NH];
#pragma unroll
    for (int j = 0; j < NH; ++j) acc[j] = 0.f;

    const float4* xr = (const float4*)(x + (size_t)node * NF);
#pragma unroll
    for (int k4 = 0; k4 < NF / 4; ++k4) {
        float4 xv = xr[k4];
        int k = k4 * 4;
#pragma unroll
        for (int j = 0; j < NH; ++j) {
            acc[j] += xv.x * w[(k + 0) * NH + j]
                    + xv.y * w[(k + 1) * NH + j]
                    + xv.z * w[(k + 2) * NH + j]
                    + xv.w * w[(k + 3) * NH + j];
        }
    }
    float4* Ar = (float4*)(A + (size_t)node * NH);
    float4* Br = (float4*)(B + (size_t)node * NH);
#pragma unroll
    for (int q = 0; q < NH / 4; ++q) {
        float4 a;
        a.x = acc[q * 4 + 0]; a.y = acc[q * 4 + 1];
        a.z = acc[q * 4 + 2]; a.w = acc[q * 4 + 3];
        Ar[q] = a;
        float4 bv;
        bv.x = a.x + bias[q * 4 + 0]; bv.y = a.y + bias[q * 4 + 1];
        bv.z = a.z + bias[q * 4 + 2]; bv.w = a.w + bias[q * 4 + 3];
        Br[q] = bv;
    }
}

// ------- Bucketing: group edges by dst>>7 into contiguous runs, packed -------
// pack = (src << 7) | (dst & 127); slot = bucket*BSTRIDE + chunkBase + rank
__global__ __launch_bounds__(1024) void k_bucket(
    const int* __restrict__ src, const int* __restrict__ dst,
    int* __restrict__ gcur, unsigned* __restrict__ gbuf) {
    __shared__ int cnt[NBUCKET];
    __shared__ int gb[NBUCKET];
    for (int i = threadIdx.x; i < NBUCKET; i += 1024) cnt[i] = 0;
    __syncthreads();

    unsigned pk[8];
    int bk[8];
    int rk[8];
    int base = blockIdx.x * EPB;
#pragma unroll
    for (int k = 0; k < 8; ++k) {
        int e = base + k * 1024 + threadIdx.x;
        bk[k] = -1;
        if (e < NE) {
            int s = src[e];
            int d = dst[e];
            int b = d >> BKT_SHIFT;
            bk[k] = b;
            pk[k] = ((unsigned)s << BKT_SHIFT) | (unsigned)(d & (BKT_NODES - 1));
            rk[k] = atomicAdd(&cnt[b], 1);   // LDS int atomic (native)
        }
    }
    __syncthreads();
    for (int b = threadIdx.x; b < NBUCKET; b += 1024) {
        int c = cnt[b];
        gb[b] = (c > 0) ? atomicAdd(&gcur[b * CUR_PAD], c) : 0;
    }
    __syncthreads();
#pragma unroll
    for (int k = 0; k < 8; ++k) {
        if (bk[k] >= 0) {
            int pos = gb[bk[k]] + rk[k];
            if (pos < BSTRIDE)   // statistically impossible overflow guard
                gbuf[(size_t)bk[k] * BSTRIDE + pos] = pk[k];
        }
    }
}

// ------- Aggregation: one block per bucket; LDS counting sort by local dst,
//         then per-node register-accumulated gather. NO f32 atomics. -------
__global__ __launch_bounds__(512) void k_agg(
    const float* __restrict__ A, float* __restrict__ B,
    const int* __restrict__ gcur, const unsigned* __restrict__ gbuf) {
    __shared__ unsigned stage[BSTRIDE];   // raw packed edges   (8 KB)
    __shared__ unsigned eSrc[BSTRIDE];    // src sorted by dl   (8 KB)
    __shared__ int cnt[BKT_NODES];
    __shared__ int off[BKT_NODES];        // inclusive scan of cnt
    __shared__ int cur[BKT_NODES];        // scatter cursor

    int b = blockIdx.x;
    int tid = threadIdx.x;
    int n = gcur[b * CUR_PAD];
    if (n > BSTRIDE) n = BSTRIDE;

    if (tid < BKT_NODES) cnt[tid] = 0;
    __syncthreads();

    // load packed edges to LDS + histogram by local dst
    for (int i = tid; i < n; i += 512) {
        unsigned u = gbuf[(size_t)b * BSTRIDE + i];
        stage[i] = u;
        atomicAdd(&cnt[u & (BKT_NODES - 1)], 1);
    }
    __syncthreads();

    // Hillis-Steele inclusive scan over 128 counters
    if (tid < BKT_NODES) off[tid] = cnt[tid];
    __syncthreads();
    for (int d = 1; d < BKT_NODES; d <<= 1) {
        int v = 0;
        if (tid < BKT_NODES && tid >= d) v = off[tid - d];
        __syncthreads();
        if (tid < BKT_NODES) off[tid] += v;
        __syncthreads();
    }
    if (tid < BKT_NODES) cur[tid] = off[tid] - cnt[tid];   // exclusive start
    __syncthreads();

    // scatter: ticket via native int LDS atomic; store src only
    for (int i = tid; i < n; i += 512) {
        unsigned u = stage[i];
        int pos = atomicAdd(&cur[u & (BKT_NODES - 1)], 1);
        eSrc[pos] = u >> BKT_SHIFT;
    }
    __syncthreads();

    // gather: 4 threads per node, register accumulation, 2-deep unroll
    int node = tid >> 2;
    int q = (tid & 3) * 4;
    int gnode = (b << BKT_SHIFT) + node;
    int end = off[node];
    int start = end - cnt[node];

    float4 bq = {0.f, 0.f, 0.f, 0.f};
    if (gnode < NN) bq = *(const float4*)(B + (size_t)gnode * NH + q);

    float4 a0 = {0.f, 0.f, 0.f, 0.f}, a1 = {0.f, 0.f, 0.f, 0.f};
    int j = start;
    for (; j + 2 <= end; j += 2) {
        int s0 = eSrc[j];
        int s1 = eSrc[j + 1];
        float4 v0 = *(const float4*)(A + (size_t)s0 * NH + q);
        float4 v1 = *(const float4*)(A + (size_t)s1 * NH + q);
        a0.x += v0.x; a0.y += v0.y; a0.z += v0.z; a0.w += v0.w;
        a1.x += v1.x; a1.y += v1.y; a1.z += v1.z; a1.w += v1.w;
    }
    if (j < end) {
        int s0 = eSrc[j];
        float4 v0 = *(const float4*)(A + (size_t)s0 * NH + q);
        a0.x += v0.x; a0.y += v0.y; a0.z += v0.z; a0.w += v0.w;
    }
    if (gnode < NN) {
        bq.x += a0.x + a1.x; bq.y += a0.y + a1.y;
        bq.z += a0.z + a1.z; bq.w += a0.w + a1.w;
        *(float4*)(B + (size_t)gnode * NH + q) = bq;
    }
}

// --- Kernel 3: h=relu(B); t=relu(h@W2+b2); z=t@W3; A=z, B=z+b3 (in place) ---
__global__ __launch_bounds__(256) void k3_mid(
    float* __restrict__ A, float* __restrict__ B,
    const float* __restrict__ W2, const float* __restrict__ b2,
    const float* __restrict__ W3, const float* __restrict__ b3) {
    __shared__ float w2[NH * NH], w3[NH * NH];
    __shared__ float bb2[NH], bb3[NH];
    for (int i = threadIdx.x; i < NH * NH; i += blockDim.x) {
        w2[i] = W2[i];
        w3[i] = W3[i];
    }
    if (threadIdx.x < NH) {
        bb2[threadIdx.x] = b2[threadIdx.x];
        bb3[threadIdx.x] = b3[threadIdx.x];
    }
    __syncthreads();
    int node = blockIdx.x * blockDim.x + threadIdx.x;
    if (node >= NN) return;

    float h[NH];
    float4* Brow = (float4*)(B + (size_t)node * NH);
#pragma unroll
    for (int q = 0; q < 4; ++q) {
        float4 v = Brow[q];
        h[q * 4 + 0] = fmaxf(v.x, 0.f);
        h[q * 4 + 1] = fmaxf(v.y, 0.f);
        h[q * 4 + 2] = fmaxf(v.z, 0.f);
        h[q * 4 + 3] = fmaxf(v.w, 0.f);
    }
    float t[NH];
#pragma unroll
    for (int j = 0; j < NH; ++j) t[j] = bb2[j];
#pragma unroll
    for (int k = 0; k < NH; ++k) {
        float hk = h[k];
#pragma unroll
        for (int j = 0; j < NH; ++j) t[j] += hk * w2[k * NH + j];
    }
#pragma unroll
    for (int j = 0; j < NH; ++j) t[j] = fmaxf(t[j], 0.f);

    float z[NH];
#pragma unroll
    for (int j = 0; j < NH; ++j) z[j] = 0.f;
#pragma unroll
    for (int k = 0; k < NH; ++k) {
        float tk = t[k];
#pragma unroll
        for (int j = 0; j < NH; ++j) z[j] += tk * w3[k * NH + j];
    }
    float4* Arow = (float4*)(A + (size_t)node * NH);
#pragma unroll
    for (int q = 0; q < 4; ++q) {
        float4 a;
        a.x = z[q * 4 + 0]; a.y = z[q * 4 + 1];
        a.z = z[q * 4 + 2]; a.w = z[q * 4 + 3];
        Arow[q] = a;
        float4 bv;
        bv.x = a.x + bb3[q * 4 + 0]; bv.y = a.y + bb3[q * 4 + 1];
        bv.z = a.z + bb3[q * 4 + 2]; bv.w = a.w + bb3[q * 4 + 3];
        Brow[q] = bv;
    }
}

// ---- Kernel 5: h=relu(B); o=h@W4+b4; out = log_softmax(o) ----
__global__ __launch_bounds__(256) void k5_out(
    const float* __restrict__ B, const float* __restrict__ W4,
    const float* __restrict__ b4, float* __restrict__ out) {
    __shared__ float w4[NH * NC];
    __shared__ float bb4[NC];
    for (int i = threadIdx.x; i < NH * NC; i += blockDim.x) w4[i] = W4[i];
    if (threadIdx.x < NC) bb4[threadIdx.x] = b4[threadIdx.x];
    __syncthreads();
    int node = blockIdx.x * blockDim.x + threadIdx.x;
    if (node >= NN) return;

    float h[NH];
    const float4* Brow = (const float4*)(B + (size_t)node * NH);
#pragma unroll
    for (int q = 0; q < 4; ++q) {
        float4 v = Brow[q];
        h[q * 4 + 0] = fmaxf(v.x, 0.f);
        h[q * 4 + 1] = fmaxf(v.y, 0.f);
        h[q * 4 + 2] = fmaxf(v.z, 0.f);
        h[q * 4 + 3] = fmaxf(v.w, 0.f);
    }
    float o[NC];
#pragma unroll
    for (int c = 0; c < NC; ++c) o[c] = bb4[c];
#pragma unroll
    for (int k = 0; k < NH; ++k) {
        float hk = h[k];
#pragma unroll
        for (int c = 0; c < NC; ++c) o[c] += hk * w4[k * NC + c];
    }
    float m = o[0];
#pragma unroll
    for (int c = 1; c < NC; ++c) m = fmaxf(m, o[c]);
    float s = 0.f;
#pragma unroll
    for (int c = 0; c < NC; ++c) s += expf(o[c] - m);
    float ls = m + logf(s);
    float* op = out + (size_t)node * NC;
#pragma unroll
    for (int c = 0; c < NC; ++c) op[c] = o[c] - ls;
}

extern "C" void kernel_launch(void* const* d_in, const int* in_sizes, int n_in,
                              void* d_out, int out_size, void* d_ws, size_t ws_size,
                              hipStream_t stream) {
    const float* x  = (const float*)d_in[0];
    const int*   ei = (const int*)d_in[1];   // [2, NE] flat: src then dst
    const float* W1 = (const float*)d_in[2];
    const float* b1 = (const float*)d_in[3];
    const float* W2 = (const float*)d_in[4];
    const float* b2 = (const float*)d_in[5];
    const float* W3 = (const float*)d_in[6];
    const float* b3 = (const float*)d_in[7];
    const float* W4 = (const float*)d_in[8];
    const float* b4 = (const float*)d_in[9];
    float* out = (float*)d_out;

    const int* src = ei;
    const int* dst = ei + NE;

    // workspace layout (16B-aligned)
    float*    A    = (float*)d_ws;                          // [NN, NH]  6.4 MB
    float*    B    = A + (size_t)NN * NH;                   // [NN, NH]  6.4 MB
    int*      gcur = (int*)(B + (size_t)NN * NH);           // [NBUCKET*16] 50 KB
    unsigned* gbuf = (unsigned*)(gcur + NBUCKET * CUR_PAD); // [NBUCKET*BSTRIDE] 6.4 MB

    const int nodeBlocks = (NN + 255) / 256;

    k1_gemm<<<nodeBlocks, 256, 0, stream>>>(x, W1, b1, A, B, gcur);
    k_bucket<<<NBLK_BUCKET, 1024, 0, stream>>>(src, dst, gcur, gbuf);

    // conv1 aggregation + MLP
    k_agg<<<NBUCKET, 512, 0, stream>>>(A, B, gcur, gbuf);
    k3_mid<<<nodeBlocks, 256, 0, stream>>>(A, B, W2, b2, W3, b3);

    // conv2 aggregation + head
    k_agg<<<NBUCKET, 512, 0, stream>>>(A, B, gcur, gbuf);
    k5_out<<<nodeBlocks, 256, 0, stream>>>(B, W4, b4, out);
}

// Round 6
// 81.538 us; speedup vs baseline: 4.0766x; 1.1992x over previous
//
#include <hip/hip_runtime.h>
#include <math.h>

constexpr int NN = 100000;   // nodes
constexpr int NE = 1250000;  // edges
constexpr int NF = 64;       // input features
constexpr int NH = 16;       // hidden
constexpr int NC = 7;        // classes

constexpr int BKT_SHIFT = 7;                 // 128 nodes per bucket
constexpr int BKT_NODES = 1 << BKT_SHIFT;    // 128
constexpr int NBUCKET = (NN + BKT_NODES - 1) / BKT_NODES;  // 782
constexpr int BSTRIDE = 2048;                // capacity per bucket (mean 1598, +11 sigma)
constexpr int EPB = 8192;                    // edges per bucketing block
constexpr int NBLK_BUCKET = (NE + EPB - 1) / EPB;          // 153
constexpr int CUR_PAD = 16;                  // pad cursors to own 64B line

// ------- Kernel 1: y = x @ W1 ; A = y, B = y + b1 ; also zero gcur -------
__global__ __launch_bounds__(256) void k1_gemm(
    const float* __restrict__ x, const float* __restrict__ W1,
    const float* __restrict__ b1, float* __restrict__ A, float* __restrict__ B,
    int* __restrict__ gcur) {
    int gtid = blockIdx.x * 256 + threadIdx.x;
    if (gtid < NBUCKET * CUR_PAD) gcur[gtid] = 0;

    __shared__ float w[NF * NH];   // 4 KB
    __shared__ float bias[NH];
    for (int i = threadIdx.x; i < NF * NH; i += blockDim.x) w[i] = W1[i];
    if (threadIdx.x < NH) bias[threadIdx.x] = b1[threadIdx.x];
    __syncthreads();
    int node = gtid;
    if (node >= NN) return;

    float acc[NH];
#pragma unroll
    for (int j = 0; j < NH; ++j) acc[j] = 0.f;

    const float4* xr = (const float4*)(x + (size_t)node * NF);
#pragma unroll
    for (int k4 = 0; k4 < NF / 4; ++k4) {
        float4 xv = xr[k4];
        int k = k4 * 4;
#pragma unroll
        for (int j = 0; j < NH; ++j) {
            acc[j] += xv.x * w[(k + 0) * NH + j]
                    + xv.y * w[(k + 1) * NH + j]
                    + xv.z * w[(k + 2) * NH + j]
                    + xv.w * w[(k + 3) * NH + j];
        }
    }
    float4* Ar = (float4*)(A + (size_t)node * NH);
    float4* Br = (float4*)(B + (size_t)node * NH);
#pragma unroll
    for (int q = 0; q < NH / 4; ++q) {
        float4 a;
        a.x = acc[q * 4 + 0]; a.y = acc[q * 4 + 1];
        a.z = acc[q * 4 + 2]; a.w = acc[q * 4 + 3];
        Ar[q] = a;
        float4 bv;
        bv.x = a.x + bias[q * 4 + 0]; bv.y = a.y + bias[q * 4 + 1];
        bv.z = a.z + bias[q * 4 + 2]; bv.w = a.w + bias[q * 4 + 3];
        Br[q] = bv;
    }
}

// ------- Bucketing with COALESCED writes: LDS counting sort by bucket,
//         then contiguous runs stream out (consecutive threads -> consecutive
//         addresses). Bucket id for a sorted slot via binary search in loff. -------
__global__ __launch_bounds__(1024) void k_bucket(
    const int* __restrict__ src, const int* __restrict__ dst,
    int* __restrict__ gcur, unsigned* __restrict__ gbuf) {
    __shared__ int cnt[NBUCKET];     // per-bucket count (this block)
    __shared__ int loff[NBUCKET];    // exclusive local offset
    __shared__ int gb[NBUCKET];      // global chunk base
    __shared__ int s[1024];          // scan buffer
    __shared__ unsigned sorted[EPB]; // 32 KB: edges sorted by bucket

    int tid = threadIdx.x;
    for (int i = tid; i < NBUCKET; i += 1024) cnt[i] = 0;
    __syncthreads();

    unsigned pk[8];
    int bk[8];
    int rk[8];
    int base = blockIdx.x * EPB;
    int nval = NE - base; if (nval > EPB) nval = EPB;
#pragma unroll
    for (int k = 0; k < 8; ++k) {
        int e = base + k * 1024 + tid;
        bk[k] = -1;
        if (e < NE) {
            int sv = src[e];
            int d = dst[e];
            int b = d >> BKT_SHIFT;
            bk[k] = b;
            pk[k] = ((unsigned)sv << BKT_SHIFT) | (unsigned)(d & (BKT_NODES - 1));
            rk[k] = atomicAdd(&cnt[b], 1);   // LDS int atomic (native)
        }
    }
    __syncthreads();

    // inclusive scan over 1024 slots (NBUCKET active)
    int v = (tid < NBUCKET) ? cnt[tid] : 0;
    s[tid] = v;
    __syncthreads();
    for (int d = 1; d < 1024; d <<= 1) {
        int u = (tid >= d) ? s[tid - d] : 0;
        __syncthreads();
        s[tid] += u;
        __syncthreads();
    }
    if (tid < NBUCKET) {
        loff[tid] = s[tid] - v;   // exclusive
        gb[tid] = (v > 0) ? atomicAdd(&gcur[tid * CUR_PAD], v) : 0;
    }
    __syncthreads();

    // scatter into sorted LDS
#pragma unroll
    for (int k = 0; k < 8; ++k) {
        if (bk[k] >= 0) sorted[loff[bk[k]] + rk[k]] = pk[k];
    }
    __syncthreads();

    // coalesced write-out: slot i -> gbuf[b*BSTRIDE + gb[b] + (i - loff[b])]
    for (int i = tid; i < nval; i += 1024) {
        int lo = 0, hi = NBUCKET - 1;          // largest b with loff[b] <= i
        while (lo < hi) {
            int mid = (lo + hi + 1) >> 1;
            if (loff[mid] <= i) lo = mid; else hi = mid - 1;
        }
        int pos = gb[lo] + (i - loff[lo]);
        if (pos < BSTRIDE)   // statistically impossible overflow guard
            gbuf[(size_t)lo * BSTRIDE + pos] = sorted[i];
    }
}

// ------- k_agg1: gather (counting-sorted, register-accumulated) FUSED with
//         mid MLP: h=relu(agg); t=relu(h@W2+b2); z=t@W3; A2=z, B=z+b3 -------
__global__ __launch_bounds__(512) void k_agg1(
    const float* __restrict__ A, float* __restrict__ B, float* __restrict__ A2,
    const int* __restrict__ gcur, const unsigned* __restrict__ gbuf,
    const float* __restrict__ W2, const float* __restrict__ b2,
    const float* __restrict__ W3, const float* __restrict__ b3) {
    __shared__ unsigned stage[BSTRIDE];   // 8 KB
    __shared__ unsigned eSrc[BSTRIDE];    // 8 KB
    __shared__ int cnt[BKT_NODES], off[BKT_NODES], cur[BKT_NODES];
    __shared__ float Bl[BKT_NODES * 17];  // aggregated h (relu'd)
    __shared__ float Tl[BKT_NODES * 17];  // t
    __shared__ float w2[NH * NH], w3[NH * NH], bb2[NH], bb3[NH];

    int b = blockIdx.x;
    int tid = threadIdx.x;
    for (int i = tid; i < NH * NH; i += 512) { w2[i] = W2[i]; w3[i] = W3[i]; }
    if (tid < NH) { bb2[tid] = b2[tid]; bb3[tid] = b3[tid]; }
    int n = gcur[b * CUR_PAD];
    if (n > BSTRIDE) n = BSTRIDE;
    if (tid < BKT_NODES) cnt[tid] = 0;
    __syncthreads();

    for (int i = tid; i < n; i += 512) {
        unsigned u = gbuf[(size_t)b * BSTRIDE + i];
        stage[i] = u;
        atomicAdd(&cnt[u & (BKT_NODES - 1)], 1);
    }
    __syncthreads();
    if (tid < BKT_NODES) off[tid] = cnt[tid];
    __syncthreads();
    for (int d = 1; d < BKT_NODES; d <<= 1) {
        int v = 0;
        if (tid < BKT_NODES && tid >= d) v = off[tid - d];
        __syncthreads();
        if (tid < BKT_NODES) off[tid] += v;
        __syncthreads();
    }
    if (tid < BKT_NODES) cur[tid] = off[tid] - cnt[tid];
    __syncthreads();
    for (int i = tid; i < n; i += 512) {
        unsigned u = stage[i];
        int pos = atomicAdd(&cur[u & (BKT_NODES - 1)], 1);
        eSrc[pos] = u >> BKT_SHIFT;
    }
    __syncthreads();

    int node = tid >> 2;
    int q = (tid & 3) * 4;
    int gnode = (b << BKT_SHIFT) + node;
    int end = off[node];
    int start = end - cnt[node];

    float4 bq = {0.f, 0.f, 0.f, 0.f};
    if (gnode < NN) bq = *(const float4*)(B + (size_t)gnode * NH + q);
    float4 a0 = {0.f, 0.f, 0.f, 0.f}, a1 = {0.f, 0.f, 0.f, 0.f};
    int j = start;
    for (; j + 2 <= end; j += 2) {
        int s0 = eSrc[j];
        int s1 = eSrc[j + 1];
        float4 v0 = *(const float4*)(A + (size_t)s0 * NH + q);
        float4 v1 = *(const float4*)(A + (size_t)s1 * NH + q);
        a0.x += v0.x; a0.y += v0.y; a0.z += v0.z; a0.w += v0.w;
        a1.x += v1.x; a1.y += v1.y; a1.z += v1.z; a1.w += v1.w;
    }
    if (j < end) {
        int s0 = eSrc[j];
        float4 v0 = *(const float4*)(A + (size_t)s0 * NH + q);
        a0.x += v0.x; a0.y += v0.y; a0.z += v0.z; a0.w += v0.w;
    }
    // h = relu(self + agg) into LDS
    Bl[node * 17 + q + 0] = fmaxf(bq.x + a0.x + a1.x, 0.f);
    Bl[node * 17 + q + 1] = fmaxf(bq.y + a0.y + a1.y, 0.f);
    Bl[node * 17 + q + 2] = fmaxf(bq.z + a0.z + a1.z, 0.f);
    Bl[node * 17 + q + 3] = fmaxf(bq.w + a0.w + a1.w, 0.f);
    __syncthreads();

    // t = relu(h@W2+b2): each thread computes 4 outputs for its node
    float t0 = bb2[q], t1 = bb2[q + 1], t2 = bb2[q + 2], t3 = bb2[q + 3];
#pragma unroll
    for (int k = 0; k < NH; ++k) {
        float hk = Bl[node * 17 + k];
        t0 += hk * w2[k * NH + q + 0];
        t1 += hk * w2[k * NH + q + 1];
        t2 += hk * w2[k * NH + q + 2];
        t3 += hk * w2[k * NH + q + 3];
    }
    Tl[node * 17 + q + 0] = fmaxf(t0, 0.f);
    Tl[node * 17 + q + 1] = fmaxf(t1, 0.f);
    Tl[node * 17 + q + 2] = fmaxf(t2, 0.f);
    Tl[node * 17 + q + 3] = fmaxf(t3, 0.f);
    __syncthreads();

    // z = t@W3 ; A2 = z, B = z + b3
    float z0 = 0.f, z1 = 0.f, z2 = 0.f, z3 = 0.f;
#pragma unroll
    for (int k = 0; k < NH; ++k) {
        float tk = Tl[node * 17 + k];
        z0 += tk * w3[k * NH + q + 0];
        z1 += tk * w3[k * NH + q + 1];
        z2 += tk * w3[k * NH + q + 2];
        z3 += tk * w3[k * NH + q + 3];
    }
    if (gnode < NN) {
        float4 az = {z0, z1, z2, z3};
        *(float4*)(A2 + (size_t)gnode * NH + q) = az;
        float4 bz = {z0 + bb3[q], z1 + bb3[q + 1], z2 + bb3[q + 2], z3 + bb3[q + 3]};
        *(float4*)(B + (size_t)gnode * NH + q) = bz;
    }
}

// ------- k_agg2: gather FUSED with head: h=relu(agg); o=h@W4+b4; log_softmax -------
__global__ __launch_bounds__(512) void k_agg2(
    const float* __restrict__ A2, const float* __restrict__ B,
    const int* __restrict__ gcur, const unsigned* __restrict__ gbuf,
    const float* __restrict__ W4, const float* __restrict__ b4,
    float* __restrict__ out) {
    __shared__ unsigned stage[BSTRIDE];
    __shared__ unsigned eSrc[BSTRIDE];
    __shared__ int cnt[BKT_NODES], off[BKT_NODES], cur[BKT_NODES];
    __shared__ float Bl[BKT_NODES * 17];
    __shared__ float w4[NH * NC];
    __shared__ float bb4[NC];

    int b = blockIdx.x;
    int tid = threadIdx.x;
    for (int i = tid; i < NH * NC; i += 512) w4[i] = W4[i];
    if (tid < NC) bb4[tid] = b4[tid];
    int n = gcur[b * CUR_PAD];
    if (n > BSTRIDE) n = BSTRIDE;
    if (tid < BKT_NODES) cnt[tid] = 0;
    __syncthreads();

    for (int i = tid; i < n; i += 512) {
        unsigned u = gbuf[(size_t)b * BSTRIDE + i];
        stage[i] = u;
        atomicAdd(&cnt[u & (BKT_NODES - 1)], 1);
    }
    __syncthreads();
    if (tid < BKT_NODES) off[tid] = cnt[tid];
    __syncthreads();
    for (int d = 1; d < BKT_NODES; d <<= 1) {
        int v = 0;
        if (tid < BKT_NODES && tid >= d) v = off[tid - d];
        __syncthreads();
        if (tid < BKT_NODES) off[tid] += v;
        __syncthreads();
    }
    if (tid < BKT_NODES) cur[tid] = off[tid] - cnt[tid];
    __syncthreads();
    for (int i = tid; i < n; i += 512) {
        unsigned u = stage[i];
        int pos = atomicAdd(&cur[u & (BKT_NODES - 1)], 1);
        eSrc[pos] = u >> BKT_SHIFT;
    }
    __syncthreads();

    int node = tid >> 2;
    int q = (tid & 3) * 4;
    int gnode = (b << BKT_SHIFT) + node;
    int end = off[node];
    int start = end - cnt[node];

    float4 bq = {0.f, 0.f, 0.f, 0.f};
    if (gnode < NN) bq = *(const float4*)(B + (size_t)gnode * NH + q);
    float4 a0 = {0.f, 0.f, 0.f, 0.f}, a1 = {0.f, 0.f, 0.f, 0.f};
    int j = start;
    for (; j + 2 <= end; j += 2) {
        int s0 = eSrc[j];
        int s1 = eSrc[j + 1];
        float4 v0 = *(const float4*)(A2 + (size_t)s0 * NH + q);
        float4 v1 = *(const float4*)(A2 + (size_t)s1 * NH + q);
        a0.x += v0.x; a0.y += v0.y; a0.z += v0.z; a0.w += v0.w;
        a1.x += v1.x; a1.y += v1.y; a1.z += v1.z; a1.w += v1.w;
    }
    if (j < end) {
        int s0 = eSrc[j];
        float4 v0 = *(const float4*)(A2 + (size_t)s0 * NH + q);
        a0.x += v0.x; a0.y += v0.y; a0.z += v0.z; a0.w += v0.w;
    }
    Bl[node * 17 + q + 0] = fmaxf(bq.x + a0.x + a1.x, 0.f);
    Bl[node * 17 + q + 1] = fmaxf(bq.y + a0.y + a1.y, 0.f);
    Bl[node * 17 + q + 2] = fmaxf(bq.z + a0.z + a1.z, 0.f);
    Bl[node * 17 + q + 3] = fmaxf(bq.w + a0.w + a1.w, 0.f);
    __syncthreads();

    // head: one thread per node
    if (tid < BKT_NODES) {
        int nd = tid;
        int gn = (b << BKT_SHIFT) + nd;
        if (gn < NN) {
            float o[NC];
#pragma unroll
            for (int c = 0; c < NC; ++c) o[c] = bb4[c];
#pragma unroll
            for (int k = 0; k < NH; ++k) {
                float hk = Bl[nd * 17 + k];
#pragma unroll
                for (int c = 0; c < NC; ++c) o[c] += hk * w4[k * NC + c];
            }
            float m = o[0];
#pragma unroll
            for (int c = 1; c < NC; ++c) m = fmaxf(m, o[c]);
            float s = 0.f;
#pragma unroll
            for (int c = 0; c < NC; ++c) s += expf(o[c] - m);
            float ls = m + logf(s);
            float* op = out + (size_t)gn * NC;
#pragma unroll
            for (int c = 0; c < NC; ++c) op[c] = o[c] - ls;
        }
    }
}

extern "C" void kernel_launch(void* const* d_in, const int* in_sizes, int n_in,
                              void* d_out, int out_size, void* d_ws, size_t ws_size,
                              hipStream_t stream) {
    const float* x  = (const float*)d_in[0];
    const int*   ei = (const int*)d_in[1];   // [2, NE] flat: src then dst
    const float* W1 = (const float*)d_in[2];
    const float* b1 = (const float*)d_in[3];
    const float* W2 = (const float*)d_in[4];
    const float* b2 = (const float*)d_in[5];
    const float* W3 = (const float*)d_in[6];
    const float* b3 = (const float*)d_in[7];
    const float* W4 = (const float*)d_in[8];
    const float* b4 = (const float*)d_in[9];
    float* out = (float*)d_out;

    const int* src = ei;
    const int* dst = ei + NE;

    // workspace layout (16B-aligned)
    float*    A    = (float*)d_ws;                          // [NN, NH]  6.4 MB
    float*    B    = A + (size_t)NN * NH;                   // [NN, NH]  6.4 MB
    float*    A2   = B + (size_t)NN * NH;                   // [NN, NH]  6.4 MB
    int*      gcur = (int*)(A2 + (size_t)NN * NH);          // [NBUCKET*16] 50 KB
    unsigned* gbuf = (unsigned*)(gcur + NBUCKET * CUR_PAD); // [NBUCKET*BSTRIDE] 6.4 MB

    const int nodeBlocks = (NN + 255) / 256;

    k1_gemm<<<nodeBlocks, 256, 0, stream>>>(x, W1, b1, A, B, gcur);
    k_bucket<<<NBLK_BUCKET, 1024, 0, stream>>>(src, dst, gcur, gbuf);
    k_agg1<<<NBUCKET, 512, 0, stream>>>(A, B, A2, gcur, gbuf, W2, b2, W3, b3);
    k_agg2<<<NBUCKET, 512, 0, stream>>>(A2, B, gcur, gbuf, W4, b4, out);
}